// Round 7
// baseline (153.118 us; speedup 1.0000x reference)
//
#include <hip/hip_runtime.h>
#include <math.h>
#include <limits.h>

#define BB 2
#define NN 16384
#define MM 4096
#define CCH 16
#define KK 32
#define R2 0.01f
#define EPSV 1e-8f
#define GD 10
#define CPB (GD*GD*GD)
#define CAP 56
#define NCELL (BB*CPB)                  // 2000
#define WSB_OFF 8192                    // bf16 w1 B-fragments (4KB)
#define BUCKET_OFF 16384
#define FEATT_OFF (2*1024*1024)
#define WS_GRID (BUCKET_OFF + (size_t)NCELL*CAP*16)     // ~1.81 MB
#define WS_FT   (FEATT_OFF + (size_t)BB*NN*CCH*4)       // 4.19 MB
#define NDW 512                          // bitmap dwords per wave (16384 bits)
#define TBL 1536                         // max candidates per query (27*56=1512)

typedef __attribute__((ext_vector_type(8))) short short8;
typedef __attribute__((ext_vector_type(4))) float v4f;

__device__ __forceinline__ short f2bf(float f) {       // RNE float->bf16
    unsigned u = __float_as_uint(f);
    unsigned r = u + 0x7FFFu + ((u >> 16) & 1u);
    return (short)(r >> 16);
}

__device__ __forceinline__ int cell_of(float x, float y, float z) {
    int cx = min(GD-1, max(0, (int)(x * 10.0f)));
    int cy = min(GD-1, max(0, (int)(y * 10.0f)));
    int cz = min(GD-1, max(0, (int)(z * 10.0f)));
    return (cx*GD + cy)*GD + cz;
}

// ws: [0]=ovf, [64..8064)=cnt[2000], [8192..12288)=w1 bf16 B-frags, [16384..)=buckets, [2MB..)=featT
__global__ void k_scatter(const float* __restrict__ xyz, const float* __restrict__ feat,
                          const float* __restrict__ w1,
                          int* __restrict__ cnt, int* __restrict__ ovf,
                          float4* __restrict__ buckets, float4* __restrict__ featT,
                          short8* __restrict__ wsB, int use_ft) {
    // one-time: pack w1 into bf16 B-fragment order (wave-invariant data)
    if (blockIdx.x == 0 && threadIdx.x < 64) {
        int l15 = threadIdx.x & 15, quad = threadIdx.x >> 4;
        #pragma unroll
        for (int u = 0; u < 4; ++u) {
            const float* wr = w1 + ((u << 4) + l15)*32 + (quad << 3);
            short8 bb;
            #pragma unroll
            for (int j = 0; j < 8; ++j) bb[j] = f2bf(wr[j]);
            wsB[threadIdx.x*4 + u] = bb;
        }
    }
    int i = blockIdx.x*256 + threadIdx.x;
    if (i >= BB*NN) return;
    const float* p = xyz + (size_t)i*3;
    int b = i >> 14;
    int n = i & (NN-1);
    float x = p[0], y = p[1], z = p[2];
    int cell = b*CPB + cell_of(x, y, z);
    int slot = atomicAdd(&cnt[cell], 1);
    if (slot < CAP)
        buckets[(size_t)cell*CAP + slot] = make_float4(x, y, z, __int_as_float(n));
    else
        *ovf = 1;
    if (use_ft) {
        const float* fb = feat + (size_t)b*CCH*NN + n;
        #pragma unroll
        for (int c4 = 0; c4 < 4; ++c4) {
            float4 t = make_float4(fb[(c4*4+0)*NN], fb[(c4*4+1)*NN],
                                   fb[(c4*4+2)*NN], fb[(c4*4+3)*NN]);
            featT[(size_t)i*4 + c4] = t;
        }
    }
}

__global__ __launch_bounds__(256, 4) void grouper_fused(
    const float* __restrict__ xyz, const float* __restrict__ new_xyz,
    const float* __restrict__ feat,
    const float* __restrict__ w0, const float* __restrict__ b0,
    const float* __restrict__ w1, const float* __restrict__ b1,
    const float* __restrict__ wxyz, const float* __restrict__ bxyz,
    const int* __restrict__ cnt, const int* __restrict__ ovf,
    const float4* __restrict__ buckets, const float4* __restrict__ featT,
    const short8* __restrict__ wsB,
    int use_grid, int use_ft,
    float* __restrict__ out)
{
    const int lane = threadIdx.x & 63;
    const int wid  = threadIdx.x >> 6;
    const int q    = (blockIdx.x << 2) + wid;
    const int b    = q >> 12;
    const int m    = q & (MM - 1);

    __shared__ int s_idx[4][KK];
    __shared__ float4 s_rel[4][KK];                      // xyz = rel, w = wk
    __shared__ __align__(16) unsigned s_bm[4][NDW];      // 2KB bitmap per wave
    __shared__ int s_tbl[4][TBL];                        // candidate slot table

    const float* xb = xyz + (size_t)b * NN * 3;
    const float qx = new_xyz[((size_t)b*MM + m)*3 + 0];
    const float qy = new_xyz[((size_t)b*MM + m)*3 + 1];
    const float qz = new_xyz[((size_t)b*MM + m)*3 + 2];
    const unsigned long long below = (1ull << lane) - 1ull;

    int nfound = 0, idx0 = 0;
    bool need_full = (use_grid == 0) || (use_grid && ovf[0] != 0);

    if (!need_full) {
        // clear this wave's bitmap
        uint4 z4 = make_uint4(0u, 0u, 0u, 0u);
        *(uint4*)&s_bm[wid][lane*8]     = z4;
        *(uint4*)&s_bm[wid][lane*8 + 4] = z4;

        int x0 = max(0, (int)floorf((qx - 0.1f)*10.0f - 1e-3f));
        int x1 = min(GD-1, (int)floorf((qx + 0.1f)*10.0f + 1e-3f));
        int y0 = max(0, (int)floorf((qy - 0.1f)*10.0f - 1e-3f));
        int y1 = min(GD-1, (int)floorf((qy + 0.1f)*10.0f + 1e-3f));
        int z0 = max(0, (int)floorf((qz - 0.1f)*10.0f - 1e-3f));
        int z1 = min(GD-1, (int)floorf((qz + 0.1f)*10.0f + 1e-3f));

        // ---- lane -> cell via arithmetic decomposition ----
        const int nz = z1 - z0 + 1, ny = y1 - y0 + 1, nx = x1 - x0 + 1;
        const int nyz = ny * nz;
        const int ncells = nx * nyz;
        const float rnyz = 1.0f / (float)nyz;
        const float rnz  = 1.0f / (float)nz;
        int myCnt = 0, myBase = 0;
        if (lane < ncells) {
            int cx = (int)((float)lane * rnyz + 1e-4f);
            int rem = lane - cx * nyz;
            int cy = (int)((float)rem * rnz + 1e-4f);
            int cz = rem - cy * nz;
            int cell = b*CPB + ((x0+cx)*GD + (y0+cy))*GD + (z0+cz);
            myCnt = min(cnt[cell], CAP);
            myBase = cell * CAP;
        }

        // ---- exclusive prefix of per-cell counts across lanes ----
        int incl = myCnt;
        #pragma unroll
        for (int d = 1; d < 64; d <<= 1) {
            int t = __shfl_up(incl, d);
            if (lane >= d) incl += t;
        }
        const int total = __shfl(incl, 63);
        int wbase = incl - myCnt;

        // ---- build candidate slot table ----
        for (int t = 0; t < myCnt; ++t) s_tbl[wid][wbase + t] = myBase + t;
        __builtin_amdgcn_wave_barrier();

        // ---- flattened candidate test, 4 per lane per iteration ----
        for (int j0 = lane; j0 < total; j0 += 256) {
            int sl[4];
            #pragma unroll
            for (int u = 0; u < 4; ++u)
                sl[u] = s_tbl[wid][min(j0 + (u << 6), total - 1)];
            float4 pt[4];
            #pragma unroll
            for (int u = 0; u < 4; ++u) pt[u] = buckets[sl[u]];
            #pragma unroll
            for (int u = 0; u < 4; ++u) {
                if (j0 + (u << 6) < total) {
                    float dx = pt[u].x - qx, dy = pt[u].y - qy, dz = pt[u].z - qz;
                    if (dx*dx + dy*dy + dz*dz < R2) {
                        int id = __float_as_int(pt[u].w);
                        atomicOr(&s_bm[wid][id >> 5], 1u << (id & 31));
                    }
                }
            }
        }

        __builtin_amdgcn_wave_barrier();

        // ---- bitmap -> first K indices (ascending). lane owns dwords [8l, 8l+8) ----
        uint4 d0 = *(uint4*)&s_bm[wid][lane*8];
        uint4 d1 = *(uint4*)&s_bm[wid][lane*8 + 4];
        unsigned dw[8] = {d0.x, d0.y, d0.z, d0.w, d1.x, d1.y, d1.z, d1.w};
        int pc = 0;
        #pragma unroll
        for (int j = 0; j < 8; ++j) pc += __popc(dw[j]);
        int pre = pc;
        #pragma unroll
        for (int d = 1; d < 64; d <<= 1) {
            int t = __shfl_up(pre, d);
            if (lane >= d) pre += t;
        }
        int tt = __shfl(pre, 63);
        int rank = pre - pc;
        nfound = min(tt, KK);

        if (rank < KK) {
            #pragma unroll
            for (int j = 0; j < 8; ++j) {
                unsigned bits = dw[j];
                while (bits && rank < KK) {
                    int bpos = __builtin_ctz(bits);
                    s_idx[wid][rank] = ((lane*8 + j) << 5) + bpos;
                    bits &= bits - 1;
                    ++rank;
                }
            }
        }

        __builtin_amdgcn_wave_barrier();
        idx0 = (nfound > 0) ? s_idx[wid][0] : 0;
        __builtin_amdgcn_wave_barrier();
        if (lane >= nfound && lane < KK) s_idx[wid][lane] = idx0;
        __builtin_amdgcn_wave_barrier();
    }

    if (need_full) {
        int cntf = 0;
        for (int basep = 0; basep < NN; basep += 256) {
            float d2a[4];
            #pragma unroll
            for (int j = 0; j < 4; ++j) {
                int i = basep + (j << 6) + lane;
                float px = xb[i*3+0], py = xb[i*3+1], pz = xb[i*3+2];
                float dx = px - qx, dy = py - qy, dz = pz - qz;
                d2a[j] = dx*dx + dy*dy + dz*dz;
            }
            #pragma unroll
            for (int j = 0; j < 4; ++j) {
                bool hit = d2a[j] < R2;
                unsigned long long msk = __ballot(hit);
                if (hit) {
                    int pos = cntf + __popcll(msk & below);
                    if (pos < KK) s_idx[wid][pos] = basep + (j << 6) + lane;
                }
                cntf += __popcll(msk);
            }
            if (cntf >= KK) break;
        }
        nfound = cntf < KK ? cntf : KK;
        __builtin_amdgcn_wave_barrier();
        if (lane < KK) {
            int v = 0;
            if (nfound > 0) v = (lane < nfound) ? s_idx[wid][lane] : s_idx[wid][0];
            s_idx[wid][lane] = v;
        }
        __builtin_amdgcn_wave_barrier();
        idx0 = s_idx[wid][0];
    }

    // ---------- rel coords + normalized weights (k = lane&31) ----------
    {
        const int k = lane & 31;
        const int h = lane >> 5;
        const int ik = s_idx[wid][k];
        float px = xb[ik*3+0], py = xb[ik*3+1], pz = xb[ik*3+2];
        float rx = px - qx, ry = py - qy, rz = pz - qz;
        float dist = sqrtf(rx*rx + ry*ry + rz*rz);
        float recip = 1.0f / (dist + EPSV);
        float mult = (float)(1 + KK - nfound);
        float w = recip / ((ik == idx0) ? mult : 1.0f);
        float S = w;
        #pragma unroll
        for (int d = 1; d < 32; d <<= 1) S += __shfl_xor(S, d);
        float wk = (nfound > 0) ? (w / S) : 0.0f;
        if (h == 0) s_rel[wid][k] = make_float4(rx, ry, rz, wk);
    }
    __builtin_amdgcn_wave_barrier();

    // ---------- MFMA MLP: lane = (l15, quad) ----------
    const int l15 = lane & 15;
    const int quad = lane >> 4;
    const int ik0 = s_idx[wid][l15];
    const int ik1 = s_idx[wid][16 + l15];

    float g0[CCH], g1[CCH];
    if (use_ft) {
        const float4* f0 = featT + ((size_t)(b*NN + ik0)) * 4;
        const float4* f1 = featT + ((size_t)(b*NN + ik1)) * 4;
        #pragma unroll
        for (int c4 = 0; c4 < 4; ++c4) {
            float4 a = f0[c4], c = f1[c4];
            g0[c4*4+0] = a.x; g0[c4*4+1] = a.y; g0[c4*4+2] = a.z; g0[c4*4+3] = a.w;
            g1[c4*4+0] = c.x; g1[c4*4+1] = c.y; g1[c4*4+2] = c.z; g1[c4*4+3] = c.w;
        }
    } else {
        const float* fb = feat + (size_t)b * CCH * NN;
        #pragma unroll
        for (int c = 0; c < CCH; ++c) { g0[c] = fb[c*NN + ik0]; g1[c] = fb[c*NN + ik1]; }
    }

    // h0 channels [8q, 8q+8) for both neighbors -> A fragments (no transpose)
    short8 A0, A1;
    #pragma unroll
    for (int j = 0; j < 8; ++j) {
        const int o = (quad << 3) + j;
        const float* wr = w0 + o*CCH;
        float a0 = 0.f, a1 = 0.f;
        #pragma unroll
        for (int c = 0; c < CCH; ++c) { a0 += wr[c]*g0[c]; a1 += wr[c]*g1[c]; }
        float bo = b0[o];
        A0[j] = f2bf(fmaxf(a0 + bo, 0.0f));
        A1[j] = f2bf(fmaxf(a1 + bo, 0.0f));
    }

    // B fragments: precomputed bf16 w1 (wave-invariant), or inline fallback
    short8 Bf[4];
    if (use_grid) {
        #pragma unroll
        for (int u = 0; u < 4; ++u) Bf[u] = wsB[lane*4 + u];
    } else {
        #pragma unroll
        for (int u = 0; u < 4; ++u) {
            const float* wr = w1 + ((u << 4) + l15)*32 + (quad << 3);
            short8 bb;
            #pragma unroll
            for (int j = 0; j < 8; ++j) bb[j] = f2bf(wr[j]);
            Bf[u] = bb;
        }
    }

    v4f zero4 = {0.f, 0.f, 0.f, 0.f};
    v4f D[2][4];
    #pragma unroll
    for (int u = 0; u < 4; ++u) {
        D[0][u] = __builtin_amdgcn_mfma_f32_16x16x32_bf16(A0, Bf[u], zero4, 0, 0, 0);
        D[1][u] = __builtin_amdgcn_mfma_f32_16x16x32_bf16(A1, Bf[u], zero4, 0, 0, 0);
    }

    // wk for this lane's 8 rows: k = 16t + 4*quad + r
    float wkv[2][4];
    #pragma unroll
    for (int t = 0; t < 2; ++t)
        #pragma unroll
        for (int r = 0; r < 4; ++r)
            wkv[t][r] = s_rel[wid][16*t + (quad << 2) + r].w;

    float* out2 = out + (size_t)BB*MM*3 + (size_t)b*96*MM;

    float Su[4];
    #pragma unroll
    for (int u = 0; u < 4; ++u) {
        const float b1O = b1[(u << 4) + l15];
        float s = 0.f;
        #pragma unroll
        for (int t = 0; t < 2; ++t)
            #pragma unroll
            for (int r = 0; r < 4; ++r)
                s += wkv[t][r] * fmaxf(D[t][u][r] + b1O, 0.0f);
        s += __shfl_xor(s, 16);
        s += __shfl_xor(s, 32);
        Su[u] = s;
    }
    float sout = (quad == 0) ? Su[0] : (quad == 1) ? Su[1] : (quad == 2) ? Su[2] : Su[3];
    out2[(32 + lane)*MM + m] = sout;   // O = 16*quad + l15 = lane

    // ---------- xyz branch: lane = channel c, halves split k, max-pool ----------
    {
        const int c = lane & 31;
        const int h = lane >> 5;
        const float wx0 = wxyz[c*3+0], wx1 = wxyz[c*3+1], wx2 = wxyz[c*3+2];
        const float bc = bxyz[c];
        float v = 0.0f;
        #pragma unroll
        for (int kk = 0; kk < 16; ++kk) {
            float4 hr = s_rel[wid][(h << 4) + kk];
            float t = bc + wx0*hr.x + wx1*hr.y + wx2*hr.z;
            v = fmaxf(v, fmaxf(t, 0.0f));
        }
        v = fmaxf(v, __shfl_xor(v, 32));
        if (h == 0) out2[c*MM + m] = v;
    }

    if (lane == 0) {
        float* o0 = out + ((size_t)b*MM + m)*3;
        o0[0] = qx; o0[1] = qy; o0[2] = qz;
    }
}

extern "C" void kernel_launch(void* const* d_in, const int* in_sizes, int n_in,
                              void* d_out, int out_size, void* d_ws, size_t ws_size,
                              hipStream_t stream) {
    const float* xyz     = (const float*)d_in[0];
    const float* new_xyz = (const float*)d_in[1];
    const float* feat    = (const float*)d_in[2];
    const float* w0      = (const float*)d_in[3];
    const float* b0      = (const float*)d_in[4];
    const float* w1      = (const float*)d_in[5];
    const float* b1      = (const float*)d_in[6];
    const float* wxyz    = (const float*)d_in[7];
    const float* bxyz    = (const float*)d_in[8];
    float* out = (float*)d_out;

    int* ovf = (int*)d_ws;
    int* cnt = (int*)((char*)d_ws + 64);
    short8* wsB = (short8*)((char*)d_ws + WSB_OFF);
    float4* buckets = (float4*)((char*)d_ws + BUCKET_OFF);
    float4* featT   = (float4*)((char*)d_ws + FEATT_OFF);
    const int use_grid = (d_ws != nullptr && ws_size >= WS_GRID) ? 1 : 0;
    const int use_ft   = (d_ws != nullptr && ws_size >= WS_FT) ? 1 : 0;

    if (use_grid) {
        hipMemsetAsync(d_ws, 0, BUCKET_OFF, stream);
        hipLaunchKernelGGL(k_scatter, dim3((BB*NN+255)/256), dim3(256), 0, stream,
                           xyz, feat, w1, cnt, ovf, buckets, featT, wsB, use_ft);
    }
    hipLaunchKernelGGL(grouper_fused, dim3((BB*MM)/4), dim3(256), 0, stream,
                       xyz, new_xyz, feat, w0, b0, w1, b1, wxyz, bxyz,
                       cnt, ovf, buckets, featT, wsB, use_grid, use_ft, out);
}